// Round 18
// baseline (85.818 us; speedup 1.0000x reference)
//
#include <hip/hip_runtime.h>
#include <hip/hip_bf16.h>
#include <cstddef>

// MoE gate: B,S,D,E,K = 4,4096,2048,64,2. N = 16384 tokens.
// out layout: dispatch [N][E][K] (2,097,152 f) | combine [N][E][K] | lbl | z
namespace {
constexpr int kD = 2048;
constexpr int kE = 64;
constexpr int kN = 16384;
constexpr size_t kDispatchFloats = (size_t)kN * kE * 2;  // 2,097,152
constexpr size_t kWsplitOff = 1024;  // float offset of W-image region in ws
}

typedef short short8_t __attribute__((ext_vector_type(8)));
typedef float f32x4 __attribute__((ext_vector_type(4)));

// fp32 -> 3 UNSCALED bf16 splits: x ~= s1 + s2 + s3 (r17-proven numerics)
__device__ __forceinline__ void split3(float f, unsigned short& s1,
                                       unsigned short& s2, unsigned short& s3) {
  __hip_bfloat16 h1 = __float2bfloat16(f);
  float r1 = f - __bfloat162float(h1);
  __hip_bfloat16 h2 = __float2bfloat16(r1);
  float r2 = r1 - __bfloat162float(h2);
  __hip_bfloat16 h3 = __float2bfloat16(r2);
  s1 = __builtin_bit_cast(unsigned short, h1);
  s2 = __builtin_bit_cast(unsigned short, h2);
  s3 = __builtin_bit_cast(unsigned short, h3);
}

// 8 floats (2x f32x4) -> one short8 per split (consumer-side convert)
__device__ __forceinline__ void split8(f32x4 a, f32x4 b, short8_t& o1,
                                       short8_t& o2, short8_t& o3) {
  unsigned short s1, s2, s3;
#define SP(v, i, j) \
  split3((v)[i], s1, s2, s3); o1[j]=(short)s1; o2[j]=(short)s2; o3[j]=(short)s3;
  SP(a, 0, 0) SP(a, 1, 1) SP(a, 2, 2) SP(a, 3, 3)
  SP(b, 0, 4) SP(b, 1, 5) SP(b, 2, 6) SP(b, 3, 7)
#undef SP
}

// ---------------------------------------------------------------------------
// Prep: zero ws + build FRAGMENT-ORDERED W image: for each
// (dq,c,kh,wc,nt,split) the 64 lanes' 16B B-fragments are CONTIGUOUS, so a
// wave's B-load is one fully-coalesced 1KB global_load_dwordx4.
//   img[(((dq*8+c)*2+kh)*12 + (wc*2+nt)*3 + split)*512 + lane*8 + j] =
//     Wsplit[wc*32+nt*16+(lane&15)][dq*512+c*64+kh*32+(lane>>4)*8+j]
__global__ __launch_bounds__(256)
void prep_kernel(const float* __restrict__ W, unsigned short* __restrict__ img,
                 float* __restrict__ ws) {
  const int t = blockIdx.x * 256 + threadIdx.x;  // 0..16383
  if (t < 512) ws[t] = 0.0f;
  const int lane = t & 63;
  const int g    = t >> 6;        // 0..255
  const int nt   = g & 1;
  const int wc   = (g >> 1) & 1;
  const int kh   = (g >> 2) & 1;
  const int c    = (g >> 3) & 7;
  const int dq   = g >> 6;
  const int e = wc * 32 + nt * 16 + (lane & 15);
  const int k = dq * 512 + c * 64 + kh * 32 + (lane >> 4) * 8;
  const float* src = W + (size_t)e * kD + k;
  const float4 v0 = *reinterpret_cast<const float4*>(src);
  const float4 v1 = *reinterpret_cast<const float4*>(src + 4);
  short8_t o1, o2, o3;
  unsigned short s1, s2, s3;
  split3(v0.x, s1, s2, s3); o1[0]=(short)s1; o2[0]=(short)s2; o3[0]=(short)s3;
  split3(v0.y, s1, s2, s3); o1[1]=(short)s1; o2[1]=(short)s2; o3[1]=(short)s3;
  split3(v0.z, s1, s2, s3); o1[2]=(short)s1; o2[2]=(short)s2; o3[2]=(short)s3;
  split3(v0.w, s1, s2, s3); o1[3]=(short)s1; o2[3]=(short)s2; o3[3]=(short)s3;
  split3(v1.x, s1, s2, s3); o1[4]=(short)s1; o2[4]=(short)s2; o3[4]=(short)s3;
  split3(v1.y, s1, s2, s3); o1[5]=(short)s1; o2[5]=(short)s2; o3[5]=(short)s3;
  split3(v1.z, s1, s2, s3); o1[6]=(short)s1; o2[6]=(short)s2; o3[6]=(short)s3;
  split3(v1.w, s1, s2, s3); o1[7]=(short)s1; o2[7]=(short)s2; o3[7]=(short)s3;
  const size_t seg = (size_t)((dq * 8 + c) * 2 + kh) * 12;
  unsigned short* base = img + (seg + (wc * 2 + nt) * 3) * 512 + lane * 8;
  *reinterpret_cast<short8_t*>(base + 0 * 512) = o1;
  *reinterpret_cast<short8_t*>(base + 1 * 512) = o2;
  *reinterpret_cast<short8_t*>(base + 2 * 512) = o3;
}

// ---------------------------------------------------------------------------
// Logits: NO LDS, NO barriers in the main loop. Grid 1024 = 256 tiles x 4 dq;
// 512 thr = 8 free-running waves (wr tok-half x wc exp-half x kh k-half).
// Per chunk per wave: 4 lane-private x loads + 6 coalesced B loads (fragment
// image), all issued ONE CHUNK AHEAD (uniform vmcnt(10) via index wrap);
// in-register split8; 12 MFMAs into a single fp32 acc. kh-halves merge once
// at the end through a small LDS buffer (the kernel's only barrier).
__global__ __launch_bounds__(512, 4)
void logits_kernel(const float* __restrict__ x,
                   const unsigned short* __restrict__ wimg,
                   float* __restrict__ out) {
  __shared__ float mbuf[64 * 65];  // 16.6 KB, used only for the final merge

  const int tid  = threadIdx.x;
  const int lane = tid & 63;
  const int wv   = __builtin_amdgcn_readfirstlane(tid >> 6);  // 0..7
  const int wr   = wv >> 2;        // token half
  const int wc   = (wv >> 1) & 1;  // expert half
  const int kh   = wv & 1;         // k-half within chunk
  const int tile = blockIdx.x & 255;
  const int dq   = blockIdx.x >> 8;
  const int lrow = lane & 15;
  const int lk   = lane >> 4;

  // x: lane-private contiguous 8-float frags for the two mt rows
  const float* __restrict__ xb0 =
      x + (size_t)(tile * 64 + wr * 32 + lrow) * kD + dq * 512 + kh * 32 + lk * 8;
  const float* __restrict__ xb1 = xb0 + (size_t)16 * kD;
  // B: fragment-ordered image, per (dq,c,kh) segment of 12x512 shorts
  const unsigned short* __restrict__ wseg =
      wimg + (size_t)((dq * 8) * 2 + kh) * 12 * 512 + (wc * 2) * 3 * 512 + lane * 8;
  // per-chunk stride in shorts: one (c) step = 2*12*512
  constexpr int kCStride = 2 * 12 * 512;

  f32x4 acc[2][2];
  const f32x4 z4 = {0.0f, 0.0f, 0.0f, 0.0f};
  acc[0][0] = z4; acc[0][1] = z4; acc[1][0] = z4; acc[1][1] = z4;

  f32x4 xc0, xc1, xc2, xc3, xn0, xn1, xn2, xn3;
  short8_t bc[6], bn[6];   // [nt*3+split]

  // prologue: chunk 0 loads
  xc0 = *reinterpret_cast<const f32x4*>(xb0);
  xc1 = *reinterpret_cast<const f32x4*>(xb0 + 4);
  xc2 = *reinterpret_cast<const f32x4*>(xb1);
  xc3 = *reinterpret_cast<const f32x4*>(xb1 + 4);
#pragma unroll
  for (int q = 0; q < 6; ++q)
    bc[q] = *reinterpret_cast<const short8_t*>(wseg + ((q / 3) * 3 + (q % 3)) * 512);

#pragma unroll 2
  for (int c = 0; c < 8; ++c) {
    const int cn = (c + 1) & 7;  // wraps -> uniform vmcnt on last iter
    // issue chunk c+1 loads (10 total) -- these are the ONLY outstanding ops
    {
      const float* p0 = xb0 + cn * 64;
      const float* p1 = xb1 + cn * 64;
      xn0 = *reinterpret_cast<const f32x4*>(p0);
      xn1 = *reinterpret_cast<const f32x4*>(p0 + 4);
      xn2 = *reinterpret_cast<const f32x4*>(p1);
      xn3 = *reinterpret_cast<const f32x4*>(p1 + 4);
      const unsigned short* ws2 = wseg + (size_t)cn * kCStride;
#pragma unroll
      for (int q = 0; q < 6; ++q)
        bn[q] = *reinterpret_cast<const short8_t*>(ws2 + ((q / 3) * 3 + (q % 3)) * 512);
    }
    __builtin_amdgcn_sched_barrier(0);
    // wait: all but the 10 just-issued -> chunk c's data is in registers
    asm volatile("s_waitcnt vmcnt(10)" ::: "memory");
    __builtin_amdgcn_sched_barrier(0);
    // compute chunk c
#pragma unroll
    for (int mt = 0; mt < 2; ++mt) {
      short8_t a1, a2, a3;
      if (mt == 0) split8(xc0, xc1, a1, a2, a3);
      else         split8(xc2, xc3, a1, a2, a3);
#pragma unroll
      for (int nt = 0; nt < 2; ++nt) {
        const short8_t b1 = bc[nt * 3 + 0];
        const short8_t b2 = bc[nt * 3 + 1];
        const short8_t b3 = bc[nt * 3 + 2];
        acc[mt][nt] = __builtin_amdgcn_mfma_f32_16x16x32_bf16(a1, b1, acc[mt][nt], 0, 0, 0);
        acc[mt][nt] = __builtin_amdgcn_mfma_f32_16x16x32_bf16(a1, b2, acc[mt][nt], 0, 0, 0);
        acc[mt][nt] = __builtin_amdgcn_mfma_f32_16x16x32_bf16(a2, b1, acc[mt][nt], 0, 0, 0);
        acc[mt][nt] = __builtin_amdgcn_mfma_f32_16x16x32_bf16(a1, b3, acc[mt][nt], 0, 0, 0);
        acc[mt][nt] = __builtin_amdgcn_mfma_f32_16x16x32_bf16(a3, b1, acc[mt][nt], 0, 0, 0);
        acc[mt][nt] = __builtin_amdgcn_mfma_f32_16x16x32_bf16(a2, b2, acc[mt][nt], 0, 0, 0);
      }
    }
    // rotate prefetch regs (renamed away by unroll-2)
    xc0 = xn0; xc1 = xn1; xc2 = xn2; xc3 = xn3;
#pragma unroll
    for (int q = 0; q < 6; ++q) bc[q] = bn[q];
  }

  // merge k-halves through LDS (the kernel's only barrier), write partials
  if (kh == 1) {
#pragma unroll
    for (int mt = 0; mt < 2; ++mt)
#pragma unroll
      for (int nt = 0; nt < 2; ++nt)
#pragma unroll
        for (int r = 0; r < 4; ++r) {
          const int trow = wr * 32 + mt * 16 + lk * 4 + r;
          const int col  = wc * 32 + nt * 16 + lrow;
          mbuf[trow * 65 + col] = acc[mt][nt][r];
        }
  }
  __syncthreads();
  if (kh == 0) {
    float* __restrict__ base = out + ((dq < 2) ? (size_t)0 : kDispatchFloats);
#pragma unroll
    for (int mt = 0; mt < 2; ++mt)
#pragma unroll
      for (int r = 0; r < 4; ++r) {
        const int trow = wr * 32 + mt * 16 + lk * 4 + r;  // C row=(lane>>4)*4+r
        const size_t n = (size_t)tile * 64 + trow;
        float* __restrict__ dst =
            base + n * 128 + (dq & 1) * 64 + wc * 32 + lrow;  // C col=lane&15
#pragma unroll
        for (int nt = 0; nt < 2; ++nt) {
          const int col = wc * 32 + nt * 16 + lrow;
          dst[nt * 16] = acc[mt][nt][r] + mbuf[trow * 65 + col];
        }
      }
  }
}

// ---------------------------------------------------------------------------
// Gate: sum 4 partials -> logits, softmax, top-2, outputs, losses.
__global__ __launch_bounds__(256)
void gate_kernel(float* __restrict__ out, float* __restrict__ ws) {
  __shared__ float lg[64][65];
  __shared__ int ti0[64], ti1[64];
  __shared__ float tv0[64], tv1[64], tz2[64];
  const int tid  = threadIdx.x;
  const int tile = blockIdx.x;

  float* __restrict__ outd = out + (size_t)tile * 8192;
  float* __restrict__ outc = out + kDispatchFloats + (size_t)tile * 8192;
  const float4* __restrict__ d4 = reinterpret_cast<const float4*>(outd);
  const float4* __restrict__ c4 = reinterpret_cast<const float4*>(outc);

  const int tq = tid >> 4, q = tid & 15;
#pragma unroll
  for (int k = 0; k < 4; ++k) {
    const int t = k * 16 + tq;
    const float4 a = d4[t * 32 + q];
    const float4 b = d4[t * 32 + 16 + q];
    const float4 c = c4[t * 32 + q];
    const float4 d = c4[t * 32 + 16 + q];
    lg[t][q * 4 + 0] = a.x + b.x + c.x + d.x;
    lg[t][q * 4 + 1] = a.y + b.y + c.y + d.y;
    lg[t][q * 4 + 2] = a.z + b.z + c.z + d.z;
    lg[t][q * 4 + 3] = a.w + b.w + c.w + d.w;
  }
  __syncthreads();

  if (tid < 64) {
    float v0 = -INFINITY, v1 = -INFINITY;
    int i0 = 0, i1 = 0;
    for (int e = 0; e < kE; ++e) {
      const float l = lg[tid][e];
      if (l > v0) { v1 = v0; i1 = i0; v0 = l; i0 = e; }
      else if (l > v1) { v1 = l; i1 = e; }
    }
    const float m = v0;
    float s = 0.0f;
    for (int e = 0; e < kE; ++e) s += __expf(lg[tid][e] - m);
    const float rs = 1.0f / s;
    float zexp = 0.0f;
    for (int e = 0; e < kE; ++e) zexp += __expf(__expf(lg[tid][e] - m) * rs);
    const float z = logf(zexp);
    ti0[tid] = i0; ti1[tid] = i1;
    tv0[tid] = rs;                    // exp(v0-m)*rs with v0==m
    tv1[tid] = __expf(v1 - m) * rs;
    tz2[tid] = z * z;
  }
  __syncthreads();

  if (tid < kE) {
    float g = 0.0f, cnt = 0.0f;
    for (int t = 0; t < 64; ++t) {
      if (ti0[t] == tid) { g += tv0[t]; cnt += 1.0f; }
      if (ti1[t] == tid) { g += tv1[t]; cnt += 1.0f; }
    }
    atomicAdd(&ws[tid], g);
    atomicAdd(&ws[kE + tid], cnt);
    float z2 = tz2[tid];
    for (int off = 32; off; off >>= 1) z2 += __shfl_down(z2, off);
    if (tid == 0) atomicAdd(&ws[2 * kE], z2);
  }

  {
    const int t = tid >> 2, sub = tid & 3;
    const int i0 = ti0[t], i1 = ti1[t];
    const float v0 = tv0[t], v1 = tv1[t];
    float4* __restrict__ dp = reinterpret_cast<float4*>(outd) + t * 32;
    float4* __restrict__ cp = reinterpret_cast<float4*>(outc) + t * 32;
#pragma unroll
    for (int j = 0; j < 8; ++j) {
      const int qq = sub * 8 + j;
      const int e0 = qq * 2, e1 = qq * 2 + 1;
      const float d0v = (e0 == i0 || e0 == i1) ? 1.0f : 0.0f;
      const float d1v = (e1 == i0 || e1 == i1) ? 1.0f : 0.0f;
      const float c0 = (e0 == i0) ? v0 : ((e0 == i1) ? v1 : 0.0f);
      const float c1 = (e1 == i0) ? v0 : ((e1 == i1) ? v1 : 0.0f);
      dp[qq] = make_float4(d0v, 0.0f, d1v, 0.0f);
      cp[qq] = make_float4(c0, 0.0f, c1, 0.0f);
    }
  }
}

// ---------------------------------------------------------------------------
__global__ void finalize_kernel(const float* __restrict__ ws,
                                float* __restrict__ out) {
  const int e = threadIdx.x;  // 64 threads
  float prod = ws[e] * ws[kE + e];
  for (int off = 32; off; off >>= 1) prod += __shfl_down(prod, off);
  if (e == 0) {
    const size_t base = kDispatchFloats * 2;
    const float invN = 1.0f / (float)kN;
    out[base]     = prod * ((float)kE * invN * invN);  // load_balancing_loss
    out[base + 1] = ws[2 * kE] * invN;                 // router_z_loss
  }
}

// ---------------------------------------------------------------------------
extern "C" void kernel_launch(void* const* d_in, const int* in_sizes, int n_in,
                              void* d_out, int out_size, void* d_ws,
                              size_t ws_size, hipStream_t stream) {
  const float* x = (const float*)d_in[0];  // [4,4096,2048] fp32
  const float* W = (const float*)d_in[1];  // [64,2048] fp32
  float* out = (float*)d_out;
  float* ws = (float*)d_ws;
  unsigned short* wimg = (unsigned short*)(ws + kWsplitOff);

  prep_kernel<<<64, 256, 0, stream>>>(W, wimg, ws);
  logits_kernel<<<1024, 512, 0, stream>>>(x, wimg, out);
  gate_kernel<<<256, 256, 0, stream>>>(out, ws);
  finalize_kernel<<<1, kE, 0, stream>>>(ws, out);
}

// Round 19
// 73.080 us; speedup vs baseline: 1.1743x; 1.1743x over previous
//
#include <hip/hip_runtime.h>
#include <hip/hip_bf16.h>
#include <cstddef>

// MoE gate: B,S,D,E,K = 4,4096,2048,64,2. N = 16384 tokens.
// out layout: dispatch [N][E][K] (2,097,152 f) | combine [N][E][K] | lbl | z
namespace {
constexpr int kD = 2048;
constexpr int kE = 64;
constexpr int kN = 16384;
constexpr size_t kDispatchFloats = (size_t)kN * kE * 2;  // 2,097,152
constexpr size_t kWsplitOff = 1024;  // float offset of W-image region in ws
}

typedef short short8_t __attribute__((ext_vector_type(8)));
typedef float f32x4 __attribute__((ext_vector_type(4)));

// fp32 -> 3 UNSCALED bf16 splits: x ~= s1 + s2 + s3 (r17-proven numerics)
__device__ __forceinline__ void split3(float f, unsigned short& s1,
                                       unsigned short& s2, unsigned short& s3) {
  __hip_bfloat16 h1 = __float2bfloat16(f);
  float r1 = f - __bfloat162float(h1);
  __hip_bfloat16 h2 = __float2bfloat16(r1);
  float r2 = r1 - __bfloat162float(h2);
  __hip_bfloat16 h3 = __float2bfloat16(r2);
  s1 = __builtin_bit_cast(unsigned short, h1);
  s2 = __builtin_bit_cast(unsigned short, h2);
  s3 = __builtin_bit_cast(unsigned short, h3);
}

// 8 floats (2x f32x4) -> one short8 per split (consumer-side convert)
__device__ __forceinline__ void split8(f32x4 a, f32x4 b, short8_t& o1,
                                       short8_t& o2, short8_t& o3) {
  unsigned short s1, s2, s3;
#define SP(v, i, j) \
  split3((v)[i], s1, s2, s3); o1[j]=(short)s1; o2[j]=(short)s2; o3[j]=(short)s3;
  SP(a, 0, 0) SP(a, 1, 1) SP(a, 2, 2) SP(a, 3, 3)
  SP(b, 0, 4) SP(b, 1, 5) SP(b, 2, 6) SP(b, 3, 7)
#undef SP
}

// ---------------------------------------------------------------------------
// Prep: zero ws accumulators + pre-split W into the swizzled LDS tile image.
// Per (dq,c): [3][64][64]-short tile; [s][row][cs8*8+j] holds
// Wsplit_s[row][(cs8 ^ (row&7))*8 + j] so a linear DMA reproduces the tile.
__global__ __launch_bounds__(256)
void prep_kernel(const float* __restrict__ W, unsigned short* __restrict__ img,
                 float* __restrict__ ws) {
  const int t = blockIdx.x * 256 + threadIdx.x;  // 0..16383
  if (t < 512) ws[t] = 0.0f;
  const int dq  = t >> 12;
  const int c   = (t >> 9) & 7;
  const int row = (t >> 3) & 63;
  const int cs8 = t & 7;
  const int co  = cs8 ^ (row & 7);
  const float* src = W + (size_t)row * kD + dq * 512 + c * 64 + co * 8;
  const float4 v0 = *reinterpret_cast<const float4*>(src);
  const float4 v1 = *reinterpret_cast<const float4*>(src + 4);
  short8_t o1, o2, o3;
  unsigned short s1, s2, s3;
  split3(v0.x, s1, s2, s3); o1[0]=(short)s1; o2[0]=(short)s2; o3[0]=(short)s3;
  split3(v0.y, s1, s2, s3); o1[1]=(short)s1; o2[1]=(short)s2; o3[1]=(short)s3;
  split3(v0.z, s1, s2, s3); o1[2]=(short)s1; o2[2]=(short)s2; o3[2]=(short)s3;
  split3(v0.w, s1, s2, s3); o1[3]=(short)s1; o2[3]=(short)s2; o3[3]=(short)s3;
  split3(v1.x, s1, s2, s3); o1[4]=(short)s1; o2[4]=(short)s2; o3[4]=(short)s3;
  split3(v1.y, s1, s2, s3); o1[5]=(short)s1; o2[5]=(short)s2; o3[5]=(short)s3;
  split3(v1.z, s1, s2, s3); o1[6]=(short)s1; o2[6]=(short)s2; o3[6]=(short)s3;
  split3(v1.w, s1, s2, s3); o1[7]=(short)s1; o2[7]=(short)s2; o3[7]=(short)s3;
  unsigned short* dst = img + (size_t)(dq * 8 + c) * 12288 + row * 64 + cs8 * 8;
  *reinterpret_cast<short8_t*>(dst + 0 * 4096) = o1;
  *reinterpret_cast<short8_t*>(dst + 1 * 4096) = o2;
  *reinterpret_cast<short8_t*>(dst + 2 * 4096) = o3;
}

// ---------------------------------------------------------------------------
// Logits (r17 structure + T5 s_setprio around the MFMA cluster).
// Grid 1024 = 256 tiles x 4 dq; 512 thr = 8 waves (wr tok-half x wc exp-half
// x kh k-half). BK=64, 8 chunks. x staged RAW fp32 (16 KB swizzled tile,
// consumer-side split8); W DMA'd from pre-swizzled image (24 KB); counted
// vmcnt(2); single fp32 accumulator. LDS 40,960 B -> 4 blocks/CU.
__global__ __launch_bounds__(512, 4)
void logits_kernel(const float* __restrict__ x,
                   const unsigned short* __restrict__ wimg,
                   float* __restrict__ out) {
  __shared__ __attribute__((aligned(16))) unsigned char smem[40960];
  float* xsf = reinterpret_cast<float*>(smem);                 // [64][64] raw x
  unsigned short (*wt)[64][64] =
      reinterpret_cast<unsigned short (*)[64][64]>(smem + 16384);  // [3][64][64]

  const int tid  = threadIdx.x;
  const int lane = tid & 63;
  const int wv   = __builtin_amdgcn_readfirstlane(tid >> 6);  // 0..7
  const int wr   = wv >> 2;        // token half
  const int wc   = (wv >> 1) & 1;  // expert half
  const int kh   = wv & 1;         // k-half within chunk
  const int tile = blockIdx.x & 255;
  const int dq   = blockIdx.x >> 8;
  const int lrow = lane & 15;
  const int lk   = lane >> 4;

  // staging role: 8 threads per token row, 8 contiguous floats each
  const int row = tid >> 3, seg = tid & 7;
  const float4* __restrict__ bx = reinterpret_cast<const float4*>(x) +
      ((size_t)tile * 64 + row) * 512 + dq * 128 + seg * 2;
  const unsigned short* __restrict__ wbase =
      wimg + (size_t)dq * 8 * 12288 + tid * 8;
  unsigned short* wtf = &wt[0][0][0];
  const int sc0 = ((2 * seg) ^ (row & 15)) * 4;      // swizzled float offsets
  const int sc1 = ((2 * seg + 1) ^ (row & 15)) * 4;

  f32x4 acc[2][2];
  const f32x4 z4 = {0.0f, 0.0f, 0.0f, 0.0f};
  acc[0][0] = z4; acc[0][1] = z4; acc[1][0] = z4; acc[1][1] = z4;

  float4 vx0 = bx[0], vx1 = bx[1];

  for (int c = 0; c < 8; ++c) {
    // 1. W-tile DMA for chunk c (3 x 16B/thread), oldest in vmcnt queue
    const unsigned short* wsrc = wbase + (size_t)c * 12288;
#pragma unroll
    for (int i = 0; i < 3; ++i)
      __builtin_amdgcn_global_load_lds(
          (const __attribute__((address_space(1))) void*)(wsrc + i * 4096),
          (__attribute__((address_space(3))) void*)(wtf + i * 4096 + wv * 512),
          16, 0, 0);
    __builtin_amdgcn_sched_barrier(0);  // pin: x-loads issue AFTER DMAs
    // 2. consume x(c) regs; issue x(c+1) prefetch (wraps -> uniform vmcnt)
    const float4 xa = vx0, xb = vx1;
    const int cn = (c + 1) & 7;
    vx0 = bx[cn * 16 + 0];
    vx1 = bx[cn * 16 + 1];
    // 3. RAW swizzled LDS store of x(c) -- no conversion here
    *reinterpret_cast<float4*>(xsf + row * 64 + sc0) = xa;
    *reinterpret_cast<float4*>(xsf + row * 64 + sc1) = xb;
    // 4. W-DMA + ds_writes drained; x(c+1) (2 loads) stays in flight
    asm volatile("s_waitcnt vmcnt(2) lgkmcnt(0)" ::: "memory");
    __builtin_amdgcn_sched_barrier(0);
    __builtin_amdgcn_s_barrier();
    __builtin_amdgcn_sched_barrier(0);
    // 5. MFMA phase: this wave's k-half (kc in 0-3 or 4-7). T5: raise wave
    //    priority through the convert+MFMA cluster so MFMA-entering waves
    //    preempt staging waves' issue slots.
    __builtin_amdgcn_s_setprio(1);
    {
      const int kc = kh * 4 + lk;
      short8_t b1[2], b2[2], b3[2];
#pragma unroll
      for (int nt = 0; nt < 2; ++nt) {
        const int e = wc * 32 + nt * 16 + lrow;
        const int cw = (kc ^ (e & 7)) * 8;
        b1[nt] = *reinterpret_cast<const short8_t*>(&wt[0][e][cw]);
        b2[nt] = *reinterpret_cast<const short8_t*>(&wt[1][e][cw]);
        b3[nt] = *reinterpret_cast<const short8_t*>(&wt[2][e][cw]);
      }
#pragma unroll
      for (int mt = 0; mt < 2; ++mt) {
        const int ra = wr * 32 + mt * 16 + lrow;
        const int ca0 = ((2 * kc) ^ (ra & 15)) * 4;
        const int ca1 = ((2 * kc + 1) ^ (ra & 15)) * 4;
        const f32x4 va = *reinterpret_cast<const f32x4*>(xsf + ra * 64 + ca0);
        const f32x4 vb = *reinterpret_cast<const f32x4*>(xsf + ra * 64 + ca1);
        short8_t a1, a2, a3;
        split8(va, vb, a1, a2, a3);
#pragma unroll
        for (int nt = 0; nt < 2; ++nt) {
          acc[mt][nt] = __builtin_amdgcn_mfma_f32_16x16x32_bf16(a1, b1[nt], acc[mt][nt], 0, 0, 0);
          acc[mt][nt] = __builtin_amdgcn_mfma_f32_16x16x32_bf16(a1, b2[nt], acc[mt][nt], 0, 0, 0);
          acc[mt][nt] = __builtin_amdgcn_mfma_f32_16x16x32_bf16(a2, b1[nt], acc[mt][nt], 0, 0, 0);
          acc[mt][nt] = __builtin_amdgcn_mfma_f32_16x16x32_bf16(a1, b3[nt], acc[mt][nt], 0, 0, 0);
          acc[mt][nt] = __builtin_amdgcn_mfma_f32_16x16x32_bf16(a3, b1[nt], acc[mt][nt], 0, 0, 0);
          acc[mt][nt] = __builtin_amdgcn_mfma_f32_16x16x32_bf16(a2, b2[nt], acc[mt][nt], 0, 0, 0);
        }
      }
    }
    __builtin_amdgcn_s_setprio(0);
    __builtin_amdgcn_sched_barrier(0);
    __builtin_amdgcn_s_barrier();  // all reads of this chunk done everywhere
  }

  // merge k-halves through the now-dead W region, write partials
  float* __restrict__ mbuf = reinterpret_cast<float*>(smem + 16384);  // [64][65]
  if (kh == 1) {
#pragma unroll
    for (int mt = 0; mt < 2; ++mt)
#pragma unroll
      for (int nt = 0; nt < 2; ++nt)
#pragma unroll
        for (int r = 0; r < 4; ++r) {
          const int trow = wr * 32 + mt * 16 + lk * 4 + r;
          const int col  = wc * 32 + nt * 16 + lrow;
          mbuf[trow * 65 + col] = acc[mt][nt][r];
        }
  }
  __syncthreads();
  if (kh == 0) {
    float* __restrict__ base = out + ((dq < 2) ? (size_t)0 : kDispatchFloats);
#pragma unroll
    for (int mt = 0; mt < 2; ++mt)
#pragma unroll
      for (int r = 0; r < 4; ++r) {
        const int trow = wr * 32 + mt * 16 + lk * 4 + r;  // C row=(lane>>4)*4+r
        const size_t n = (size_t)tile * 64 + trow;
        float* __restrict__ dst =
            base + n * 128 + (dq & 1) * 64 + wc * 32 + lrow;  // C col=lane&15
#pragma unroll
        for (int nt = 0; nt < 2; ++nt) {
          const int col = wc * 32 + nt * 16 + lrow;
          dst[nt * 16] = acc[mt][nt][r] + mbuf[trow * 65 + col];
        }
      }
  }
}

// ---------------------------------------------------------------------------
// Gate: sum 4 partials -> logits, softmax, top-2, outputs, losses.
__global__ __launch_bounds__(256)
void gate_kernel(float* __restrict__ out, float* __restrict__ ws) {
  __shared__ float lg[64][65];
  __shared__ int ti0[64], ti1[64];
  __shared__ float tv0[64], tv1[64], tz2[64];
  const int tid  = threadIdx.x;
  const int tile = blockIdx.x;

  float* __restrict__ outd = out + (size_t)tile * 8192;
  float* __restrict__ outc = out + kDispatchFloats + (size_t)tile * 8192;
  const float4* __restrict__ d4 = reinterpret_cast<const float4*>(outd);
  const float4* __restrict__ c4 = reinterpret_cast<const float4*>(outc);

  const int tq = tid >> 4, q = tid & 15;
#pragma unroll
  for (int k = 0; k < 4; ++k) {
    const int t = k * 16 + tq;
    const float4 a = d4[t * 32 + q];
    const float4 b = d4[t * 32 + 16 + q];
    const float4 c = c4[t * 32 + q];
    const float4 d = c4[t * 32 + 16 + q];
    lg[t][q * 4 + 0] = a.x + b.x + c.x + d.x;
    lg[t][q * 4 + 1] = a.y + b.y + c.y + d.y;
    lg[t][q * 4 + 2] = a.z + b.z + c.z + d.z;
    lg[t][q * 4 + 3] = a.w + b.w + c.w + d.w;
  }
  __syncthreads();

  if (tid < 64) {
    float v0 = -INFINITY, v1 = -INFINITY;
    int i0 = 0, i1 = 0;
    for (int e = 0; e < kE; ++e) {
      const float l = lg[tid][e];
      if (l > v0) { v1 = v0; i1 = i0; v0 = l; i0 = e; }
      else if (l > v1) { v1 = l; i1 = e; }
    }
    const float m = v0;
    float s = 0.0f;
    for (int e = 0; e < kE; ++e) s += __expf(lg[tid][e] - m);
    const float rs = 1.0f / s;
    float zexp = 0.0f;
    for (int e = 0; e < kE; ++e) zexp += __expf(__expf(lg[tid][e] - m) * rs);
    const float z = logf(zexp);
    ti0[tid] = i0; ti1[tid] = i1;
    tv0[tid] = rs;                    // exp(v0-m)*rs with v0==m
    tv1[tid] = __expf(v1 - m) * rs;
    tz2[tid] = z * z;
  }
  __syncthreads();

  if (tid < kE) {
    float g = 0.0f, cnt = 0.0f;
    for (int t = 0; t < 64; ++t) {
      if (ti0[t] == tid) { g += tv0[t]; cnt += 1.0f; }
      if (ti1[t] == tid) { g += tv1[t]; cnt += 1.0f; }
    }
    atomicAdd(&ws[tid], g);
    atomicAdd(&ws[kE + tid], cnt);
    float z2 = tz2[tid];
    for (int off = 32; off; off >>= 1) z2 += __shfl_down(z2, off);
    if (tid == 0) atomicAdd(&ws[2 * kE], z2);
  }

  {
    const int t = tid >> 2, sub = tid & 3;
    const int i0 = ti0[t], i1 = ti1[t];
    const float v0 = tv0[t], v1 = tv1[t];
    float4* __restrict__ dp = reinterpret_cast<float4*>(outd) + t * 32;
    float4* __restrict__ cp = reinterpret_cast<float4*>(outc) + t * 32;
#pragma unroll
    for (int j = 0; j < 8; ++j) {
      const int qq = sub * 8 + j;
      const int e0 = qq * 2, e1 = qq * 2 + 1;
      const float d0v = (e0 == i0 || e0 == i1) ? 1.0f : 0.0f;
      const float d1v = (e1 == i0 || e1 == i1) ? 1.0f : 0.0f;
      const float c0 = (e0 == i0) ? v0 : ((e0 == i1) ? v1 : 0.0f);
      const float c1 = (e1 == i0) ? v0 : ((e1 == i1) ? v1 : 0.0f);
      dp[qq] = make_float4(d0v, 0.0f, d1v, 0.0f);
      cp[qq] = make_float4(c0, 0.0f, c1, 0.0f);
    }
  }
}

// ---------------------------------------------------------------------------
__global__ void finalize_kernel(const float* __restrict__ ws,
                                float* __restrict__ out) {
  const int e = threadIdx.x;  // 64 threads
  float prod = ws[e] * ws[kE + e];
  for (int off = 32; off; off >>= 1) prod += __shfl_down(prod, off);
  if (e == 0) {
    const size_t base = kDispatchFloats * 2;
    const float invN = 1.0f / (float)kN;
    out[base]     = prod * ((float)kE * invN * invN);  // load_balancing_loss
    out[base + 1] = ws[2 * kE] * invN;                 // router_z_loss
  }
}

// ---------------------------------------------------------------------------
extern "C" void kernel_launch(void* const* d_in, const int* in_sizes, int n_in,
                              void* d_out, int out_size, void* d_ws,
                              size_t ws_size, hipStream_t stream) {
  const float* x = (const float*)d_in[0];  // [4,4096,2048] fp32
  const float* W = (const float*)d_in[1];  // [64,2048] fp32
  float* out = (float*)d_out;
  float* ws = (float*)d_ws;
  unsigned short* wimg = (unsigned short*)(ws + kWsplitOff);

  prep_kernel<<<64, 256, 0, stream>>>(W, wimg, ws);
  logits_kernel<<<1024, 512, 0, stream>>>(x, wimg, out);
  gate_kernel<<<256, 256, 0, stream>>>(out, ws);
  finalize_kernel<<<1, kE, 0, stream>>>(ws, out);
}

// Round 20
// 72.906 us; speedup vs baseline: 1.1771x; 1.0024x over previous
//
#include <hip/hip_runtime.h>
#include <hip/hip_bf16.h>
#include <cstddef>

// MoE gate: B,S,D,E,K = 4,4096,2048,64,2. N = 16384 tokens.
// out layout: dispatch [N][E][K] (2,097,152 f) | combine [N][E][K] | lbl | z
namespace {
constexpr int kD = 2048;
constexpr int kE = 64;
constexpr int kN = 16384;
constexpr size_t kDispatchFloats = (size_t)kN * kE * 2;  // 2,097,152
constexpr size_t kWsplitOff = 1024;  // float offset of W-image region in ws
}

typedef short short8_t __attribute__((ext_vector_type(8)));
typedef float f32x4 __attribute__((ext_vector_type(4)));

// fp32 -> 3 UNSCALED bf16 splits: x ~= s1 + s2 + s3 (r17-proven numerics)
__device__ __forceinline__ void split3(float f, unsigned short& s1,
                                       unsigned short& s2, unsigned short& s3) {
  __hip_bfloat16 h1 = __float2bfloat16(f);
  float r1 = f - __bfloat162float(h1);
  __hip_bfloat16 h2 = __float2bfloat16(r1);
  float r2 = r1 - __bfloat162float(h2);
  __hip_bfloat16 h3 = __float2bfloat16(r2);
  s1 = __builtin_bit_cast(unsigned short, h1);
  s2 = __builtin_bit_cast(unsigned short, h2);
  s3 = __builtin_bit_cast(unsigned short, h3);
}

// 8 floats (2x f32x4) -> one short8 per split (consumer-side convert)
__device__ __forceinline__ void split8(f32x4 a, f32x4 b, short8_t& o1,
                                       short8_t& o2, short8_t& o3) {
  unsigned short s1, s2, s3;
#define SP(v, i, j) \
  split3((v)[i], s1, s2, s3); o1[j]=(short)s1; o2[j]=(short)s2; o3[j]=(short)s3;
  SP(a, 0, 0) SP(a, 1, 1) SP(a, 2, 2) SP(a, 3, 3)
  SP(b, 0, 4) SP(b, 1, 5) SP(b, 2, 6) SP(b, 3, 7)
#undef SP
}

// ---------------------------------------------------------------------------
// Prep: zero ws accumulators + pre-split W into the swizzled LDS tile image.
// Per (dq,c): [3][64][64]-short tile; [s][row][cs8*8+j] holds
// Wsplit_s[row][(cs8 ^ (row&7))*8 + j] so a linear DMA reproduces the tile.
__global__ __launch_bounds__(256)
void prep_kernel(const float* __restrict__ W, unsigned short* __restrict__ img,
                 float* __restrict__ ws) {
  const int t = blockIdx.x * 256 + threadIdx.x;  // 0..16383
  if (t < 512) ws[t] = 0.0f;
  const int dq  = t >> 12;
  const int c   = (t >> 9) & 7;
  const int row = (t >> 3) & 63;
  const int cs8 = t & 7;
  const int co  = cs8 ^ (row & 7);
  const float* src = W + (size_t)row * kD + dq * 512 + c * 64 + co * 8;
  const float4 v0 = *reinterpret_cast<const float4*>(src);
  const float4 v1 = *reinterpret_cast<const float4*>(src + 4);
  short8_t o1, o2, o3;
  unsigned short s1, s2, s3;
  split3(v0.x, s1, s2, s3); o1[0]=(short)s1; o2[0]=(short)s2; o3[0]=(short)s3;
  split3(v0.y, s1, s2, s3); o1[1]=(short)s1; o2[1]=(short)s2; o3[1]=(short)s3;
  split3(v0.z, s1, s2, s3); o1[2]=(short)s1; o2[2]=(short)s2; o3[2]=(short)s3;
  split3(v0.w, s1, s2, s3); o1[3]=(short)s1; o2[3]=(short)s2; o3[3]=(short)s3;
  split3(v1.x, s1, s2, s3); o1[4]=(short)s1; o2[4]=(short)s2; o3[4]=(short)s3;
  split3(v1.y, s1, s2, s3); o1[5]=(short)s1; o2[5]=(short)s2; o3[5]=(short)s3;
  split3(v1.z, s1, s2, s3); o1[6]=(short)s1; o2[6]=(short)s2; o3[6]=(short)s3;
  split3(v1.w, s1, s2, s3); o1[7]=(short)s1; o2[7]=(short)s2; o3[7]=(short)s3;
  unsigned short* dst = img + (size_t)(dq * 8 + c) * 12288 + row * 64 + cs8 * 8;
  *reinterpret_cast<short8_t*>(dst + 0 * 4096) = o1;
  *reinterpret_cast<short8_t*>(dst + 1 * 4096) = o2;
  *reinterpret_cast<short8_t*>(dst + 2 * 4096) = o3;
}

// ---------------------------------------------------------------------------
// Logits, T=128 token tiles (halves per-CU W-tile re-DMA line traffic — the
// dominant L1-line consumer per the r6..r19 line-rate model).
// Grid 512 = 128 tiles x 4 dq; 512 thr = 8 waves (wr tok-half-of-128 x
// wc exp-half x kh k-half). BK=64, 8 chunks. x staged RAW fp32 (32 KB
// swizzled tile, consumer-side split8); W DMA'd from pre-swizzled image
// (24 KB); counted vmcnt(4); single fp32 accumulator (mt=4). 56 KB LDS.
__global__ __launch_bounds__(512, 2)
void logits_kernel(const float* __restrict__ x,
                   const unsigned short* __restrict__ wimg,
                   float* __restrict__ out) {
  __shared__ __attribute__((aligned(16))) unsigned char smem[57344];
  float* xsf = reinterpret_cast<float*>(smem);                 // [128][64] raw x
  unsigned short (*wt)[64][64] =
      reinterpret_cast<unsigned short (*)[64][64]>(smem + 32768);  // [3][64][64]

  const int tid  = threadIdx.x;
  const int lane = tid & 63;
  const int wv   = __builtin_amdgcn_readfirstlane(tid >> 6);  // 0..7
  const int wr   = wv >> 2;        // token half (64 rows each)
  const int wc   = (wv >> 1) & 1;  // expert half
  const int kh   = wv & 1;         // k-half within chunk
  const int tile = blockIdx.x & 127;
  const int dq   = blockIdx.x >> 7;
  const int lrow = lane & 15;
  const int lk   = lane >> 4;

  // staging role: 4 threads per token row, 16 contiguous floats each
  const int row = tid >> 2, seg = tid & 3;
  const float4* __restrict__ bx = reinterpret_cast<const float4*>(x) +
      ((size_t)tile * 128 + row) * 512 + dq * 128 + seg * 4;
  const unsigned short* __restrict__ wbase =
      wimg + (size_t)dq * 8 * 12288 + tid * 8;
  unsigned short* wtf = &wt[0][0][0];
  // swizzled float offsets for the 4 16B units this thread stages
  int sc[4];
#pragma unroll
  for (int j = 0; j < 4; ++j) sc[j] = ((seg * 4 + j) ^ (row & 15)) * 4;

  f32x4 acc[4][2];
  const f32x4 z4 = {0.0f, 0.0f, 0.0f, 0.0f};
#pragma unroll
  for (int mt = 0; mt < 4; ++mt) { acc[mt][0] = z4; acc[mt][1] = z4; }

  float4 vx0 = bx[0], vx1 = bx[1], vx2 = bx[2], vx3 = bx[3];

  for (int c = 0; c < 8; ++c) {
    // 1. W-tile DMA for chunk c (3 x 16B/thread), oldest in vmcnt queue
    const unsigned short* wsrc = wbase + (size_t)c * 12288;
#pragma unroll
    for (int i = 0; i < 3; ++i)
      __builtin_amdgcn_global_load_lds(
          (const __attribute__((address_space(1))) void*)(wsrc + i * 4096),
          (__attribute__((address_space(3))) void*)(wtf + i * 4096 + wv * 512),
          16, 0, 0);
    __builtin_amdgcn_sched_barrier(0);  // pin: x-loads issue AFTER DMAs
    // 2. consume x(c) regs; issue x(c+1) prefetch (wraps -> uniform vmcnt)
    const float4 xa = vx0, xb = vx1, xc2 = vx2, xd = vx3;
    const int cn = (c + 1) & 7;
    vx0 = bx[cn * 16 + 0]; vx1 = bx[cn * 16 + 1];
    vx2 = bx[cn * 16 + 2]; vx3 = bx[cn * 16 + 3];
    // 3. RAW swizzled LDS store of x(c) -- no conversion here
    *reinterpret_cast<float4*>(xsf + row * 64 + sc[0]) = xa;
    *reinterpret_cast<float4*>(xsf + row * 64 + sc[1]) = xb;
    *reinterpret_cast<float4*>(xsf + row * 64 + sc[2]) = xc2;
    *reinterpret_cast<float4*>(xsf + row * 64 + sc[3]) = xd;
    // 4. W-DMA + ds_writes drained; x(c+1) (4 loads) stays in flight
    asm volatile("s_waitcnt vmcnt(4) lgkmcnt(0)" ::: "memory");
    __builtin_amdgcn_sched_barrier(0);
    __builtin_amdgcn_s_barrier();
    __builtin_amdgcn_sched_barrier(0);
    // 5. MFMA phase: this wave's k-half (kc in 0-3 or 4-7), 4 mt rows
    __builtin_amdgcn_s_setprio(1);
    {
      const int kc = kh * 4 + lk;
      short8_t b1[2], b2[2], b3[2];
#pragma unroll
      for (int nt = 0; nt < 2; ++nt) {
        const int e = wc * 32 + nt * 16 + lrow;
        const int cw = (kc ^ (e & 7)) * 8;
        b1[nt] = *reinterpret_cast<const short8_t*>(&wt[0][e][cw]);
        b2[nt] = *reinterpret_cast<const short8_t*>(&wt[1][e][cw]);
        b3[nt] = *reinterpret_cast<const short8_t*>(&wt[2][e][cw]);
      }
#pragma unroll
      for (int mt = 0; mt < 4; ++mt) {
        const int ra = wr * 64 + mt * 16 + lrow;
        const int ca0 = ((2 * kc) ^ (ra & 15)) * 4;
        const int ca1 = ((2 * kc + 1) ^ (ra & 15)) * 4;
        const f32x4 va = *reinterpret_cast<const f32x4*>(xsf + ra * 64 + ca0);
        const f32x4 vb = *reinterpret_cast<const f32x4*>(xsf + ra * 64 + ca1);
        short8_t a1, a2, a3;
        split8(va, vb, a1, a2, a3);
#pragma unroll
        for (int nt = 0; nt < 2; ++nt) {
          acc[mt][nt] = __builtin_amdgcn_mfma_f32_16x16x32_bf16(a1, b1[nt], acc[mt][nt], 0, 0, 0);
          acc[mt][nt] = __builtin_amdgcn_mfma_f32_16x16x32_bf16(a1, b2[nt], acc[mt][nt], 0, 0, 0);
          acc[mt][nt] = __builtin_amdgcn_mfma_f32_16x16x32_bf16(a2, b1[nt], acc[mt][nt], 0, 0, 0);
          acc[mt][nt] = __builtin_amdgcn_mfma_f32_16x16x32_bf16(a1, b3[nt], acc[mt][nt], 0, 0, 0);
          acc[mt][nt] = __builtin_amdgcn_mfma_f32_16x16x32_bf16(a3, b1[nt], acc[mt][nt], 0, 0, 0);
          acc[mt][nt] = __builtin_amdgcn_mfma_f32_16x16x32_bf16(a2, b2[nt], acc[mt][nt], 0, 0, 0);
        }
      }
    }
    __builtin_amdgcn_s_setprio(0);
    __builtin_amdgcn_sched_barrier(0);
    __builtin_amdgcn_s_barrier();  // all reads of this chunk done everywhere
  }

  // merge k-halves through the now-dead smem (float [128][65] = 33,280 B)
  float* __restrict__ mbuf = reinterpret_cast<float*>(smem);
  __syncthreads();  // everyone past the K loop before overwriting x tile
  if (kh == 1) {
#pragma unroll
    for (int mt = 0; mt < 4; ++mt)
#pragma unroll
      for (int nt = 0; nt < 2; ++nt)
#pragma unroll
        for (int r = 0; r < 4; ++r) {
          const int trow = wr * 64 + mt * 16 + lk * 4 + r;
          const int col  = wc * 32 + nt * 16 + lrow;
          mbuf[trow * 65 + col] = acc[mt][nt][r];
        }
  }
  __syncthreads();
  if (kh == 0) {
    float* __restrict__ base = out + ((dq < 2) ? (size_t)0 : kDispatchFloats);
#pragma unroll
    for (int mt = 0; mt < 4; ++mt)
#pragma unroll
      for (int r = 0; r < 4; ++r) {
        const int trow = wr * 64 + mt * 16 + lk * 4 + r;  // C row=(lane>>4)*4+r
        const size_t n = (size_t)tile * 128 + trow;
        float* __restrict__ dst =
            base + n * 128 + (dq & 1) * 64 + wc * 32 + lrow;  // C col=lane&15
#pragma unroll
        for (int nt = 0; nt < 2; ++nt) {
          const int col = wc * 32 + nt * 16 + lrow;
          dst[nt * 16] = acc[mt][nt][r] + mbuf[trow * 65 + col];
        }
      }
  }
}

// ---------------------------------------------------------------------------
// Gate: sum 4 partials -> logits, softmax, top-2, outputs, losses.
__global__ __launch_bounds__(256)
void gate_kernel(float* __restrict__ out, float* __restrict__ ws) {
  __shared__ float lg[64][65];
  __shared__ int ti0[64], ti1[64];
  __shared__ float tv0[64], tv1[64], tz2[64];
  const int tid  = threadIdx.x;
  const int tile = blockIdx.x;

  float* __restrict__ outd = out + (size_t)tile * 8192;
  float* __restrict__ outc = out + kDispatchFloats + (size_t)tile * 8192;
  const float4* __restrict__ d4 = reinterpret_cast<const float4*>(outd);
  const float4* __restrict__ c4 = reinterpret_cast<const float4*>(outc);

  const int tq = tid >> 4, q = tid & 15;
#pragma unroll
  for (int k = 0; k < 4; ++k) {
    const int t = k * 16 + tq;
    const float4 a = d4[t * 32 + q];
    const float4 b = d4[t * 32 + 16 + q];
    const float4 c = c4[t * 32 + q];
    const float4 d = c4[t * 32 + 16 + q];
    lg[t][q * 4 + 0] = a.x + b.x + c.x + d.x;
    lg[t][q * 4 + 1] = a.y + b.y + c.y + d.y;
    lg[t][q * 4 + 2] = a.z + b.z + c.z + d.z;
    lg[t][q * 4 + 3] = a.w + b.w + c.w + d.w;
  }
  __syncthreads();

  if (tid < 64) {
    float v0 = -INFINITY, v1 = -INFINITY;
    int i0 = 0, i1 = 0;
    for (int e = 0; e < kE; ++e) {
      const float l = lg[tid][e];
      if (l > v0) { v1 = v0; i1 = i0; v0 = l; i0 = e; }
      else if (l > v1) { v1 = l; i1 = e; }
    }
    const float m = v0;
    float s = 0.0f;
    for (int e = 0; e < kE; ++e) s += __expf(lg[tid][e] - m);
    const float rs = 1.0f / s;
    float zexp = 0.0f;
    for (int e = 0; e < kE; ++e) zexp += __expf(__expf(lg[tid][e] - m) * rs);
    const float z = logf(zexp);
    ti0[tid] = i0; ti1[tid] = i1;
    tv0[tid] = rs;                    // exp(v0-m)*rs with v0==m
    tv1[tid] = __expf(v1 - m) * rs;
    tz2[tid] = z * z;
  }
  __syncthreads();

  if (tid < kE) {
    float g = 0.0f, cnt = 0.0f;
    for (int t = 0; t < 64; ++t) {
      if (ti0[t] == tid) { g += tv0[t]; cnt += 1.0f; }
      if (ti1[t] == tid) { g += tv1[t]; cnt += 1.0f; }
    }
    atomicAdd(&ws[tid], g);
    atomicAdd(&ws[kE + tid], cnt);
    float z2 = tz2[tid];
    for (int off = 32; off; off >>= 1) z2 += __shfl_down(z2, off);
    if (tid == 0) atomicAdd(&ws[2 * kE], z2);
  }

  {
    const int t = tid >> 2, sub = tid & 3;
    const int i0 = ti0[t], i1 = ti1[t];
    const float v0 = tv0[t], v1 = tv1[t];
    float4* __restrict__ dp = reinterpret_cast<float4*>(outd) + t * 32;
    float4* __restrict__ cp = reinterpret_cast<float4*>(outc) + t * 32;
#pragma unroll
    for (int j = 0; j < 8; ++j) {
      const int qq = sub * 8 + j;
      const int e0 = qq * 2, e1 = qq * 2 + 1;
      const float d0v = (e0 == i0 || e0 == i1) ? 1.0f : 0.0f;
      const float d1v = (e1 == i0 || e1 == i1) ? 1.0f : 0.0f;
      const float c0 = (e0 == i0) ? v0 : ((e0 == i1) ? v1 : 0.0f);
      const float c1 = (e1 == i0) ? v0 : ((e1 == i1) ? v1 : 0.0f);
      dp[qq] = make_float4(d0v, 0.0f, d1v, 0.0f);
      cp[qq] = make_float4(c0, 0.0f, c1, 0.0f);
    }
  }
}

// ---------------------------------------------------------------------------
__global__ void finalize_kernel(const float* __restrict__ ws,
                                float* __restrict__ out) {
  const int e = threadIdx.x;  // 64 threads
  float prod = ws[e] * ws[kE + e];
  for (int off = 32; off; off >>= 1) prod += __shfl_down(prod, off);
  if (e == 0) {
    const size_t base = kDispatchFloats * 2;
    const float invN = 1.0f / (float)kN;
    out[base]     = prod * ((float)kE * invN * invN);  // load_balancing_loss
    out[base + 1] = ws[2 * kE] * invN;                 // router_z_loss
  }
}

// ---------------------------------------------------------------------------
extern "C" void kernel_launch(void* const* d_in, const int* in_sizes, int n_in,
                              void* d_out, int out_size, void* d_ws,
                              size_t ws_size, hipStream_t stream) {
  const float* x = (const float*)d_in[0];  // [4,4096,2048] fp32
  const float* W = (const float*)d_in[1];  // [64,2048] fp32
  float* out = (float*)d_out;
  float* ws = (float*)d_ws;
  unsigned short* wimg = (unsigned short*)(ws + kWsplitOff);

  prep_kernel<<<64, 256, 0, stream>>>(W, wimg, ws);
  logits_kernel<<<512, 512, 0, stream>>>(x, wimg, out);
  gate_kernel<<<256, 256, 0, stream>>>(out, ws);
  finalize_kernel<<<1, kE, 0, stream>>>(ws, out);
}

// Round 21
// 69.291 us; speedup vs baseline: 1.2385x; 1.0522x over previous
//
#include <hip/hip_runtime.h>
#include <hip/hip_bf16.h>
#include <cstddef>

// MoE gate: B,S,D,E,K = 4,4096,2048,64,2. N = 16384 tokens.
// out layout: dispatch [N][E][K] (2,097,152 f) | combine [N][E][K] | lbl | z
namespace {
constexpr int kD = 2048;
constexpr int kE = 64;
constexpr int kN = 16384;
constexpr size_t kDispatchFloats = (size_t)kN * kE * 2;  // 2,097,152
constexpr size_t kWsplitOff = 1024;  // float offset of W-image region in ws
}

typedef short short8_t __attribute__((ext_vector_type(8)));
typedef float f32x4 __attribute__((ext_vector_type(4)));

// fp32 -> 3 UNSCALED bf16 splits: x ~= s1 + s2 + s3 (r17-proven numerics)
__device__ __forceinline__ void split3(float f, unsigned short& s1,
                                       unsigned short& s2, unsigned short& s3) {
  __hip_bfloat16 h1 = __float2bfloat16(f);
  float r1 = f - __bfloat162float(h1);
  __hip_bfloat16 h2 = __float2bfloat16(r1);
  float r2 = r1 - __bfloat162float(h2);
  __hip_bfloat16 h3 = __float2bfloat16(r2);
  s1 = __builtin_bit_cast(unsigned short, h1);
  s2 = __builtin_bit_cast(unsigned short, h2);
  s3 = __builtin_bit_cast(unsigned short, h3);
}

// 8 floats (2x f32x4) -> one short8 per split (consumer-side convert)
__device__ __forceinline__ void split8(f32x4 a, f32x4 b, short8_t& o1,
                                       short8_t& o2, short8_t& o3) {
  unsigned short s1, s2, s3;
#define SP(v, i, j) \
  split3((v)[i], s1, s2, s3); o1[j]=(short)s1; o2[j]=(short)s2; o3[j]=(short)s3;
  SP(a, 0, 0) SP(a, 1, 1) SP(a, 2, 2) SP(a, 3, 3)
  SP(b, 0, 4) SP(b, 1, 5) SP(b, 2, 6) SP(b, 3, 7)
#undef SP
}

// ---------------------------------------------------------------------------
// Prep: zero ws accumulators + pre-split W into the swizzled LDS tile image.
// Tile g (= k/64, k-LINEAR) is [3][64][64] shorts; [s][row][cs8*8+j] holds
// Wsplit_s[row][g*64 + (cs8 ^ (row&7))*8 + j] so a linear DMA reproduces it.
__global__ __launch_bounds__(256)
void prep_kernel(const float* __restrict__ W, unsigned short* __restrict__ img,
                 float* __restrict__ ws) {
  const int t = blockIdx.x * 256 + threadIdx.x;  // 0..16383
  if (t < 512) ws[t] = 0.0f;
  const int g   = t >> 9;         // k-linear tile 0..31
  const int row = (t >> 3) & 63;
  const int cs8 = t & 7;
  const int co  = cs8 ^ (row & 7);
  const float* src = W + (size_t)row * kD + g * 64 + co * 8;
  const float4 v0 = *reinterpret_cast<const float4*>(src);
  const float4 v1 = *reinterpret_cast<const float4*>(src + 4);
  short8_t o1, o2, o3;
  unsigned short s1, s2, s3;
  split3(v0.x, s1, s2, s3); o1[0]=(short)s1; o2[0]=(short)s2; o3[0]=(short)s3;
  split3(v0.y, s1, s2, s3); o1[1]=(short)s1; o2[1]=(short)s2; o3[1]=(short)s3;
  split3(v0.z, s1, s2, s3); o1[2]=(short)s1; o2[2]=(short)s2; o3[2]=(short)s3;
  split3(v0.w, s1, s2, s3); o1[3]=(short)s1; o2[3]=(short)s2; o3[3]=(short)s3;
  split3(v1.x, s1, s2, s3); o1[4]=(short)s1; o2[4]=(short)s2; o3[4]=(short)s3;
  split3(v1.y, s1, s2, s3); o1[5]=(short)s1; o2[5]=(short)s2; o3[5]=(short)s3;
  split3(v1.z, s1, s2, s3); o1[6]=(short)s1; o2[6]=(short)s2; o3[6]=(short)s3;
  split3(v1.w, s1, s2, s3); o1[7]=(short)s1; o2[7]=(short)s2; o3[7]=(short)s3;
  unsigned short* dst = img + (size_t)g * 12288 + row * 64 + cs8 * 8;
  *reinterpret_cast<short8_t*>(dst + 0 * 4096) = o1;
  *reinterpret_cast<short8_t*>(dst + 1 * 4096) = o2;
  *reinterpret_cast<short8_t*>(dst + 2 * 4096) = o3;
}

// ---------------------------------------------------------------------------
// Fused logits+gate, NO partials, NO cross-block dependency (no fences).
// Grid 512 = 32-token tiles; 512 thr = 8 waves (th tok-group x wc exp-half x
// kh k-half). 16 iterations x 128 k: x raw fp32 [32][128] swizzled (16 KB),
// W = 2 k-linear image tiles DMA'd (48 KB). 64 KB LDS -> 2 blocks/CU, one
// clean grid pass. After the K loop: kh-merge in LDS, in-block softmax/top-2,
// outputs, loss atomics. r17 numerics (absmax 2.4e-4 class).
__global__ __launch_bounds__(512, 2)
void moe_kernel(const float* __restrict__ x,
                const unsigned short* __restrict__ wimg,
                float* __restrict__ out, float* __restrict__ ws) {
  __shared__ __attribute__((aligned(16))) unsigned char smem[65536];
  float* xsf = reinterpret_cast<float*>(smem);  // [32][128] raw x (16 KB)
  unsigned short (*wt)[3][64][64] =
      reinterpret_cast<unsigned short (*)[3][64][64]>(smem + 16384);  // 2x24KB
  float (*lg)[65] = reinterpret_cast<float (*)[65]>(smem);  // reuse x region
  __shared__ int ti0[32], ti1[32];
  __shared__ float tv0[32], tv1[32], tz2[32];

  const int tid  = threadIdx.x;
  const int lane = tid & 63;
  const int wv   = __builtin_amdgcn_readfirstlane(tid >> 6);  // 0..7
  const int th   = wv >> 2;        // token group (16 rows)
  const int wc   = (wv >> 1) & 1;  // expert half
  const int kh   = wv & 1;         // k-half within 128-k iteration
  const int tile = blockIdx.x;     // 0..511
  const int lrow = lane & 15;
  const int lk   = lane >> 4;

  // staging role: 16 threads per token row, 8 contiguous floats each
  const int row = tid >> 4, t16 = tid & 15;
  const float4* __restrict__ bx = reinterpret_cast<const float4*>(x) +
      ((size_t)tile * 32 + row) * 512 + t16 * 2;
  const unsigned short* __restrict__ wbase = wimg + tid * 8;
  unsigned short* wtf = &wt[0][0][0][0];
  const int su0 = ((2 * t16) ^ (row & 31)) * 4;      // swizzled float offsets
  const int su1 = ((2 * t16 + 1) ^ (row & 31)) * 4;

  f32x4 acc[2];
  const f32x4 z4 = {0.0f, 0.0f, 0.0f, 0.0f};
  acc[0] = z4; acc[1] = z4;

  float4 vx0 = bx[0], vx1 = bx[1];

  for (int c = 0; c < 16; ++c) {
    // 1. W DMA: 2 k-linear tiles (g = 2c, 2c+1), 6 x 16B/thread
    const unsigned short* wsrc = wbase + (size_t)(2 * c) * 12288;
#pragma unroll
    for (int i = 0; i < 6; ++i)
      __builtin_amdgcn_global_load_lds(
          (const __attribute__((address_space(1))) void*)(wsrc + i * 4096),
          (__attribute__((address_space(3))) void*)(wtf + i * 4096 + wv * 512),
          16, 0, 0);
    __builtin_amdgcn_sched_barrier(0);  // pin: x-loads issue AFTER DMAs
    // 2. consume x(c) regs; issue x(c+1) prefetch (wraps -> uniform vmcnt)
    const float4 xa = vx0, xb = vx1;
    const int cn = (c + 1) & 15;
    vx0 = bx[cn * 32 + 0];
    vx1 = bx[cn * 32 + 1];
    // 3. RAW swizzled LDS store of x(c)
    *reinterpret_cast<float4*>(xsf + row * 128 + su0) = xa;
    *reinterpret_cast<float4*>(xsf + row * 128 + su1) = xb;
    // 4. W-DMA + ds_writes drained; x(c+1) (2 loads) stays in flight
    asm volatile("s_waitcnt vmcnt(2) lgkmcnt(0)" ::: "memory");
    __builtin_amdgcn_sched_barrier(0);
    __builtin_amdgcn_s_barrier();
    __builtin_amdgcn_sched_barrier(0);
    // 5. MFMA: this wave's 64-k half (wt[kh]); 2 ks x 2 nt x 6 products
    __builtin_amdgcn_s_setprio(1);
#pragma unroll
    for (int ks = 0; ks < 2; ++ks) {
      const int kc = ks * 4 + lk;     // 0..7 within wt[kh]
      short8_t b1[2], b2[2], b3[2];
#pragma unroll
      for (int nt = 0; nt < 2; ++nt) {
        const int e = wc * 32 + nt * 16 + lrow;
        const int cw = (kc ^ (e & 7)) * 8;
        b1[nt] = *reinterpret_cast<const short8_t*>(&wt[kh][0][e][cw]);
        b2[nt] = *reinterpret_cast<const short8_t*>(&wt[kh][1][e][cw]);
        b3[nt] = *reinterpret_cast<const short8_t*>(&wt[kh][2][e][cw]);
      }
      const int ra = th * 16 + lrow;
      const int u0 = kh * 16 + ks * 8 + 2 * lk;  // 16B unit within 128-k row
      const int ca0 = ((u0) ^ (ra & 31)) * 4;
      const int ca1 = ((u0 + 1) ^ (ra & 31)) * 4;
      const f32x4 va = *reinterpret_cast<const f32x4*>(xsf + ra * 128 + ca0);
      const f32x4 vb = *reinterpret_cast<const f32x4*>(xsf + ra * 128 + ca1);
      short8_t a1, a2, a3;
      split8(va, vb, a1, a2, a3);
#pragma unroll
      for (int nt = 0; nt < 2; ++nt) {
        acc[nt] = __builtin_amdgcn_mfma_f32_16x16x32_bf16(a1, b1[nt], acc[nt], 0, 0, 0);
        acc[nt] = __builtin_amdgcn_mfma_f32_16x16x32_bf16(a1, b2[nt], acc[nt], 0, 0, 0);
        acc[nt] = __builtin_amdgcn_mfma_f32_16x16x32_bf16(a2, b1[nt], acc[nt], 0, 0, 0);
        acc[nt] = __builtin_amdgcn_mfma_f32_16x16x32_bf16(a1, b3[nt], acc[nt], 0, 0, 0);
        acc[nt] = __builtin_amdgcn_mfma_f32_16x16x32_bf16(a3, b1[nt], acc[nt], 0, 0, 0);
        acc[nt] = __builtin_amdgcn_mfma_f32_16x16x32_bf16(a2, b2[nt], acc[nt], 0, 0, 0);
      }
    }
    __builtin_amdgcn_s_setprio(0);
    __builtin_amdgcn_sched_barrier(0);
    __builtin_amdgcn_s_barrier();  // all reads of this iteration done
  }

  // ---- kh-merge into lg[32][65] (reuses x region; K loop fully done) ------
  if (kh == 1) {
#pragma unroll
    for (int nt = 0; nt < 2; ++nt)
#pragma unroll
      for (int r = 0; r < 4; ++r)
        lg[th * 16 + lk * 4 + r][wc * 32 + nt * 16 + lrow] = acc[nt][r];
  }
  __syncthreads();
  if (kh == 0) {
#pragma unroll
    for (int nt = 0; nt < 2; ++nt)
#pragma unroll
      for (int r = 0; r < 4; ++r) {
        const int t = th * 16 + lk * 4 + r;
        const int e = wc * 32 + nt * 16 + lrow;
        lg[t][e] += acc[nt][r];
      }
  }
  __syncthreads();

  // ---- in-block gate: softmax + top-2 + z (32 tokens) ---------------------
  if (tid < 32) {
    float v0 = -INFINITY, v1 = -INFINITY;
    int i0 = 0, i1 = 0;
    for (int e = 0; e < kE; ++e) {
      const float l = lg[tid][e];
      if (l > v0) { v1 = v0; i1 = i0; v0 = l; i0 = e; }
      else if (l > v1) { v1 = l; i1 = e; }
    }
    const float m = v0;
    float s = 0.0f;
    for (int e = 0; e < kE; ++e) s += __expf(lg[tid][e] - m);
    const float rs = 1.0f / s;
    float zexp = 0.0f;
    for (int e = 0; e < kE; ++e) zexp += __expf(__expf(lg[tid][e] - m) * rs);
    const float z = logf(zexp);
    ti0[tid] = i0; ti1[tid] = i1;
    tv0[tid] = rs;                    // exp(v0-m)*rs with v0==m
    tv1[tid] = __expf(v1 - m) * rs;
    tz2[tid] = z * z;
  }
  __syncthreads();

  // losses: thread = expert (deterministic in-block order); z2 via wave 0
  if (tid < kE) {
    float g = 0.0f, cnt = 0.0f;
    for (int t = 0; t < 32; ++t) {
      if (ti0[t] == tid) { g += tv0[t]; cnt += 1.0f; }
      if (ti1[t] == tid) { g += tv1[t]; cnt += 1.0f; }
    }
    atomicAdd(&ws[tid], g);
    atomicAdd(&ws[kE + tid], cnt);
  }
  if (tid < 32) {
    float z2 = tz2[tid];
    z2 += __shfl_down(z2, 16);
    z2 += __shfl_down(z2, 8);
    z2 += __shfl_down(z2, 4);
    z2 += __shfl_down(z2, 2);
    z2 += __shfl_down(z2, 1);
    if (tid == 0) atomicAdd(&ws[2 * kE], z2);
  }

  // outputs: 16 threads/token, 2 float4 per tensor each, coalesced
  {
    const int t = tid >> 4, sub = tid & 15;
    const int i0 = ti0[t], i1 = ti1[t];
    const float v0 = tv0[t], v1 = tv1[t];
    const size_t n = (size_t)tile * 32 + t;
    float4* __restrict__ dp = reinterpret_cast<float4*>(out) + n * 32;
    float4* __restrict__ cp =
        reinterpret_cast<float4*>(out) + kDispatchFloats / 4 + n * 32;
#pragma unroll
    for (int j = 0; j < 2; ++j) {
      const int qq = sub * 2 + j;
      const int e0 = qq * 2, e1 = qq * 2 + 1;
      const float d0v = (e0 == i0 || e0 == i1) ? 1.0f : 0.0f;
      const float d1v = (e1 == i0 || e1 == i1) ? 1.0f : 0.0f;
      const float c0 = (e0 == i0) ? v0 : ((e0 == i1) ? v1 : 0.0f);
      const float c1 = (e1 == i0) ? v0 : ((e1 == i1) ? v1 : 0.0f);
      dp[qq] = make_float4(d0v, 0.0f, d1v, 0.0f);
      cp[qq] = make_float4(c0, 0.0f, c1, 0.0f);
    }
  }
}

// ---------------------------------------------------------------------------
__global__ void finalize_kernel(const float* __restrict__ ws,
                                float* __restrict__ out) {
  const int e = threadIdx.x;  // 64 threads
  float prod = ws[e] * ws[kE + e];
  for (int off = 32; off; off >>= 1) prod += __shfl_down(prod, off);
  if (e == 0) {
    const size_t base = kDispatchFloats * 2;
    const float invN = 1.0f / (float)kN;
    out[base]     = prod * ((float)kE * invN * invN);  // load_balancing_loss
    out[base + 1] = ws[2 * kE] * invN;                 // router_z_loss
  }
}

// ---------------------------------------------------------------------------
extern "C" void kernel_launch(void* const* d_in, const int* in_sizes, int n_in,
                              void* d_out, int out_size, void* d_ws,
                              size_t ws_size, hipStream_t stream) {
  const float* x = (const float*)d_in[0];  // [4,4096,2048] fp32
  const float* W = (const float*)d_in[1];  // [64,2048] fp32
  float* out = (float*)d_out;
  float* ws = (float*)d_ws;
  unsigned short* wimg = (unsigned short*)(ws + kWsplitOff);

  prep_kernel<<<64, 256, 0, stream>>>(W, wimg, ws);
  moe_kernel<<<512, 512, 0, stream>>>(x, wimg, out, ws);
  finalize_kernel<<<1, kE, 0, stream>>>(ws, out);
}

// Round 22
// 65.654 us; speedup vs baseline: 1.3071x; 1.0554x over previous
//
#include <hip/hip_runtime.h>
#include <hip/hip_bf16.h>
#include <cstddef>

// MoE gate: B,S,D,E,K = 4,4096,2048,64,2. N = 16384 tokens.
// out layout: dispatch [N][E][K] (2,097,152 f) | combine [N][E][K] | lbl | z
namespace {
constexpr int kD = 2048;
constexpr int kE = 64;
constexpr int kN = 16384;
constexpr size_t kDispatchFloats = (size_t)kN * kE * 2;  // 2,097,152
constexpr size_t kWsplitOff = 1024;  // float offset of W-image region in ws
}

typedef short short8_t __attribute__((ext_vector_type(8)));
typedef float f32x4 __attribute__((ext_vector_type(4)));

// fp32 -> 2 UNSCALED bf16 splits: x ~= s1 + s2 (captures ~16 mantissa bits).
// Dropped 3rd term contributes ~2^-16|x| -> logit error ~3e-5 over K=2048.
__device__ __forceinline__ void split2(float f, unsigned short& s1,
                                       unsigned short& s2) {
  __hip_bfloat16 h1 = __float2bfloat16(f);
  float r1 = f - __bfloat162float(h1);
  __hip_bfloat16 h2 = __float2bfloat16(r1);
  s1 = __builtin_bit_cast(unsigned short, h1);
  s2 = __builtin_bit_cast(unsigned short, h2);
}

// 8 floats (2x f32x4) -> one short8 per split (consumer-side convert)
__device__ __forceinline__ void split8_2(f32x4 a, f32x4 b, short8_t& o1,
                                         short8_t& o2) {
  unsigned short s1, s2;
#define SP(v, i, j) \
  split2((v)[i], s1, s2); o1[j] = (short)s1; o2[j] = (short)s2;
  SP(a, 0, 0) SP(a, 1, 1) SP(a, 2, 2) SP(a, 3, 3)
  SP(b, 0, 4) SP(b, 1, 5) SP(b, 2, 6) SP(b, 3, 7)
#undef SP
}

// ---------------------------------------------------------------------------
// Prep: zero ws accumulators + pre-split W (2 splits) into the swizzled LDS
// tile image. Tile g (= k/64, k-linear) is [2][64][64] shorts (16 KB);
// [s][row][cs8*8+j] holds Wsplit_s[row][g*64 + (cs8 ^ (row&7))*8 + j] so a
// linear global_load_lds DMA reproduces the swizzled tile verbatim.
__global__ __launch_bounds__(256)
void prep_kernel(const float* __restrict__ W, unsigned short* __restrict__ img,
                 float* __restrict__ ws) {
  const int t = blockIdx.x * 256 + threadIdx.x;  // 0..16383
  if (t < 512) ws[t] = 0.0f;
  const int g   = t >> 9;         // k-linear tile 0..31
  const int row = (t >> 3) & 63;
  const int cs8 = t & 7;
  const int co  = cs8 ^ (row & 7);
  const float* src = W + (size_t)row * kD + g * 64 + co * 8;
  const float4 v0 = *reinterpret_cast<const float4*>(src);
  const float4 v1 = *reinterpret_cast<const float4*>(src + 4);
  short8_t o1, o2;
  unsigned short s1, s2;
  split2(v0.x, s1, s2); o1[0]=(short)s1; o2[0]=(short)s2;
  split2(v0.y, s1, s2); o1[1]=(short)s1; o2[1]=(short)s2;
  split2(v0.z, s1, s2); o1[2]=(short)s1; o2[2]=(short)s2;
  split2(v0.w, s1, s2); o1[3]=(short)s1; o2[3]=(short)s2;
  split2(v1.x, s1, s2); o1[4]=(short)s1; o2[4]=(short)s2;
  split2(v1.y, s1, s2); o1[5]=(short)s1; o2[5]=(short)s2;
  split2(v1.z, s1, s2); o1[6]=(short)s1; o2[6]=(short)s2;
  split2(v1.w, s1, s2); o1[7]=(short)s1; o2[7]=(short)s2;
  unsigned short* dst = img + (size_t)g * 8192 + row * 64 + cs8 * 8;
  *reinterpret_cast<short8_t*>(dst + 0 * 4096) = o1;
  *reinterpret_cast<short8_t*>(dst + 1 * 4096) = o2;
}

// ---------------------------------------------------------------------------
// Fused logits+gate (r21 structure, DOUBLE-split numerics -> per-wave work
// halved: 12 MFMAs + 8 B-reads + 2-level converts per iteration).
// Grid 512 = 32-token tiles; 512 thr = 8 waves (th tok-group x wc exp-half x
// kh k-half). 16 iterations x 128 k: x raw fp32 [32][128] swizzled (16 KB),
// W = 2 k-linear image tiles DMA'd (32 KB). 48 KB LDS -> 3 blocks/CU.
__global__ __launch_bounds__(512, 6)
void moe_kernel(const float* __restrict__ x,
                const unsigned short* __restrict__ wimg,
                float* __restrict__ out, float* __restrict__ ws) {
  __shared__ __attribute__((aligned(16))) unsigned char smem[49152];
  float* xsf = reinterpret_cast<float*>(smem);  // [32][128] raw x (16 KB)
  unsigned short (*wt)[2][64][64] =
      reinterpret_cast<unsigned short (*)[2][64][64]>(smem + 16384);  // 2x16KB
  float (*lg)[65] = reinterpret_cast<float (*)[65]>(smem);  // reuse x region
  __shared__ int ti0[32], ti1[32];
  __shared__ float tv0[32], tv1[32], tz2[32];

  const int tid  = threadIdx.x;
  const int lane = tid & 63;
  const int wv   = __builtin_amdgcn_readfirstlane(tid >> 6);  // 0..7
  const int th   = wv >> 2;        // token group (16 rows)
  const int wc   = (wv >> 1) & 1;  // expert half
  const int kh   = wv & 1;         // k-half within 128-k iteration
  const int tile = blockIdx.x;     // 0..511
  const int lrow = lane & 15;
  const int lk   = lane >> 4;

  // staging role: 16 threads per token row, 8 contiguous floats each
  const int row = tid >> 4, t16 = tid & 15;
  const float4* __restrict__ bx = reinterpret_cast<const float4*>(x) +
      ((size_t)tile * 32 + row) * 512 + t16 * 2;
  const unsigned short* __restrict__ wbase = wimg + tid * 8;
  unsigned short* wtf = &wt[0][0][0][0];
  const int su0 = ((2 * t16) ^ (row & 31)) * 4;      // swizzled float offsets
  const int su1 = ((2 * t16 + 1) ^ (row & 31)) * 4;

  f32x4 acc[2];
  const f32x4 z4 = {0.0f, 0.0f, 0.0f, 0.0f};
  acc[0] = z4; acc[1] = z4;

  float4 vx0 = bx[0], vx1 = bx[1];

  for (int c = 0; c < 16; ++c) {
    // 1. W DMA: 2 k-linear tiles (g = 2c, 2c+1), 4 x 16B/thread (32 KB)
    const unsigned short* wsrc = wbase + (size_t)(2 * c) * 8192;
#pragma unroll
    for (int i = 0; i < 4; ++i)
      __builtin_amdgcn_global_load_lds(
          (const __attribute__((address_space(1))) void*)(wsrc + i * 4096),
          (__attribute__((address_space(3))) void*)(wtf + i * 4096 + wv * 512),
          16, 0, 0);
    __builtin_amdgcn_sched_barrier(0);  // pin: x-loads issue AFTER DMAs
    // 2. consume x(c) regs; issue x(c+1) prefetch (wraps -> uniform vmcnt)
    const float4 xa = vx0, xb = vx1;
    const int cn = (c + 1) & 15;
    vx0 = bx[cn * 32 + 0];
    vx1 = bx[cn * 32 + 1];
    // 3. RAW swizzled LDS store of x(c)
    *reinterpret_cast<float4*>(xsf + row * 128 + su0) = xa;
    *reinterpret_cast<float4*>(xsf + row * 128 + su1) = xb;
    // 4. W-DMA + ds_writes drained; x(c+1) (2 loads) stays in flight
    asm volatile("s_waitcnt vmcnt(2) lgkmcnt(0)" ::: "memory");
    __builtin_amdgcn_sched_barrier(0);
    __builtin_amdgcn_s_barrier();
    __builtin_amdgcn_sched_barrier(0);
    // 5. MFMA: this wave's 64-k half (wt[kh]); 2 ks x 2 nt x 3 products
    __builtin_amdgcn_s_setprio(1);
#pragma unroll
    for (int ks = 0; ks < 2; ++ks) {
      const int kc = ks * 4 + lk;     // 0..7 within wt[kh]
      short8_t b1[2], b2[2];
#pragma unroll
      for (int nt = 0; nt < 2; ++nt) {
        const int e = wc * 32 + nt * 16 + lrow;
        const int cw = (kc ^ (e & 7)) * 8;
        b1[nt] = *reinterpret_cast<const short8_t*>(&wt[kh][0][e][cw]);
        b2[nt] = *reinterpret_cast<const short8_t*>(&wt[kh][1][e][cw]);
      }
      const int ra = th * 16 + lrow;
      const int u0 = kh * 16 + ks * 8 + 2 * lk;  // 16B unit within 128-k row
      const int ca0 = ((u0) ^ (ra & 31)) * 4;
      const int ca1 = ((u0 + 1) ^ (ra & 31)) * 4;
      const f32x4 va = *reinterpret_cast<const f32x4*>(xsf + ra * 128 + ca0);
      const f32x4 vb = *reinterpret_cast<const f32x4*>(xsf + ra * 128 + ca1);
      short8_t a1, a2;
      split8_2(va, vb, a1, a2);
#pragma unroll
      for (int nt = 0; nt < 2; ++nt) {
        acc[nt] = __builtin_amdgcn_mfma_f32_16x16x32_bf16(a1, b1[nt], acc[nt], 0, 0, 0);
        acc[nt] = __builtin_amdgcn_mfma_f32_16x16x32_bf16(a1, b2[nt], acc[nt], 0, 0, 0);
        acc[nt] = __builtin_amdgcn_mfma_f32_16x16x32_bf16(a2, b1[nt], acc[nt], 0, 0, 0);
      }
    }
    __builtin_amdgcn_s_setprio(0);
    __builtin_amdgcn_sched_barrier(0);
    __builtin_amdgcn_s_barrier();  // all reads of this iteration done
  }

  // ---- kh-merge into lg[32][65] (reuses x region; K loop fully done) ------
  if (kh == 1) {
#pragma unroll
    for (int nt = 0; nt < 2; ++nt)
#pragma unroll
      for (int r = 0; r < 4; ++r)
        lg[th * 16 + lk * 4 + r][wc * 32 + nt * 16 + lrow] = acc[nt][r];
  }
  __syncthreads();
  if (kh == 0) {
#pragma unroll
    for (int nt = 0; nt < 2; ++nt)
#pragma unroll
      for (int r = 0; r < 4; ++r) {
        const int t = th * 16 + lk * 4 + r;
        const int e = wc * 32 + nt * 16 + lrow;
        lg[t][e] += acc[nt][r];
      }
  }
  __syncthreads();

  // ---- in-block gate: softmax + top-2 + z (32 tokens) ---------------------
  if (tid < 32) {
    float v0 = -INFINITY, v1 = -INFINITY;
    int i0 = 0, i1 = 0;
    for (int e = 0; e < kE; ++e) {
      const float l = lg[tid][e];
      if (l > v0) { v1 = v0; i1 = i0; v0 = l; i0 = e; }
      else if (l > v1) { v1 = l; i1 = e; }
    }
    const float m = v0;
    float s = 0.0f;
    for (int e = 0; e < kE; ++e) s += __expf(lg[tid][e] - m);
    const float rs = 1.0f / s;
    float zexp = 0.0f;
    for (int e = 0; e < kE; ++e) zexp += __expf(__expf(lg[tid][e] - m) * rs);
    const float z = logf(zexp);
    ti0[tid] = i0; ti1[tid] = i1;
    tv0[tid] = rs;                    // exp(v0-m)*rs with v0==m
    tv1[tid] = __expf(v1 - m) * rs;
    tz2[tid] = z * z;
  }
  __syncthreads();

  // losses: thread = expert (deterministic in-block order); z2 via wave 0
  if (tid < kE) {
    float g = 0.0f, cnt = 0.0f;
    for (int t = 0; t < 32; ++t) {
      if (ti0[t] == tid) { g += tv0[t]; cnt += 1.0f; }
      if (ti1[t] == tid) { g += tv1[t]; cnt += 1.0f; }
    }
    atomicAdd(&ws[tid], g);
    atomicAdd(&ws[kE + tid], cnt);
  }
  if (tid < 32) {
    float z2 = tz2[tid];
    z2 += __shfl_down(z2, 16);
    z2 += __shfl_down(z2, 8);
    z2 += __shfl_down(z2, 4);
    z2 += __shfl_down(z2, 2);
    z2 += __shfl_down(z2, 1);
    if (tid == 0) atomicAdd(&ws[2 * kE], z2);
  }

  // outputs: 16 threads/token, 2 float4 per tensor each, coalesced
  {
    const int t = tid >> 4, sub = tid & 15;
    const int i0 = ti0[t], i1 = ti1[t];
    const float v0 = tv0[t], v1 = tv1[t];
    const size_t n = (size_t)tile * 32 + t;
    float4* __restrict__ dp = reinterpret_cast<float4*>(out) + n * 32;
    float4* __restrict__ cp =
        reinterpret_cast<float4*>(out) + kDispatchFloats / 4 + n * 32;
#pragma unroll
    for (int j = 0; j < 2; ++j) {
      const int qq = sub * 2 + j;
      const int e0 = qq * 2, e1 = qq * 2 + 1;
      const float d0v = (e0 == i0 || e0 == i1) ? 1.0f : 0.0f;
      const float d1v = (e1 == i0 || e1 == i1) ? 1.0f : 0.0f;
      const float c0 = (e0 == i0) ? v0 : ((e0 == i1) ? v1 : 0.0f);
      const float c1 = (e1 == i0) ? v0 : ((e1 == i1) ? v1 : 0.0f);
      dp[qq] = make_float4(d0v, 0.0f, d1v, 0.0f);
      cp[qq] = make_float4(c0, 0.0f, c1, 0.0f);
    }
  }
}

// ---------------------------------------------------------------------------
__global__ void finalize_kernel(const float* __restrict__ ws,
                                float* __restrict__ out) {
  const int e = threadIdx.x;  // 64 threads
  float prod = ws[e] * ws[kE + e];
  for (int off = 32; off; off >>= 1) prod += __shfl_down(prod, off);
  if (e == 0) {
    const size_t base = kDispatchFloats * 2;
    const float invN = 1.0f / (float)kN;
    out[base]     = prod * ((float)kE * invN * invN);  // load_balancing_loss
    out[base + 1] = ws[2 * kE] * invN;                 // router_z_loss
  }
}

// ---------------------------------------------------------------------------
extern "C" void kernel_launch(void* const* d_in, const int* in_sizes, int n_in,
                              void* d_out, int out_size, void* d_ws,
                              size_t ws_size, hipStream_t stream) {
  const float* x = (const float*)d_in[0];  // [4,4096,2048] fp32
  const float* W = (const float*)d_in[1];  // [64,2048] fp32
  float* out = (float*)d_out;
  float* ws = (float*)d_ws;
  unsigned short* wimg = (unsigned short*)(ws + kWsplitOff);

  prep_kernel<<<64, 256, 0, stream>>>(W, wimg, ws);
  moe_kernel<<<512, 512, 0, stream>>>(x, wimg, out, ws);
  finalize_kernel<<<1, kE, 0, stream>>>(ws, out);
}